// Round 12
// baseline (1163.461 us; speedup 1.0000x reference)
//
#include <hip/hip_runtime.h>

// TemporalCausalMaps on MI355X (gfx950), round 15 (= r14 resubmit; r14 bench
// was an infra failure "container failed twice", same as r6 which passed
// unchanged on resubmit). Hardened for compile cost: unroll pragmas removed
// from runtime-strided item loops; run_iter<L> noinline (emitted once per
// instantiation). The t-indexed loops stay fully unrolled via constexpr L.
//
// Design (from r13/r14): dual-sample wave, 1024 blocks x 1 wave.
//  - r13 verdict: ILP x2 == TLP x2 == ~1040us; streams/SIMD capped at 2 by
//    the sample count. Lever now: per-stream duty + instruction count.
//  - L = idx+1 made COMPILE-TIME via template<int L> + switch(idx):
//    t-loops fully unroll, LDS loads batch across t, loop overhead gone.
//  - wide stages dual-stream (weights shared between the 2 samples);
//    group-parallel stages sample=lane-group; lgkm-only SYNC (1 wave).

#define NT 64
#define SYNC() asm volatile("s_waitcnt lgkmcnt(0)" ::: "memory")

// per-sample LDS region offsets (floats); region stride 3488 (16B-aligned)
#define SS   3488
#define OX   0      // s_x   [8][48]
#define OH   384    // s_h   [8][24]
#define OG   576    // s_g   [8][24]
#define OGI  768    // s_gi  [8][72]
#define OY   1344   // s_y   [8][24]
#define OHID 1536   // s_hid [2][24]
#define OD1  1584   // s_d1  [8][68]
#define OD2  2128   // s_d2  [8][68]
#define ODD  2672   // s_dd  [16]
#define OCH  2688   // s_ch  [8][36]
#define OEMB 2976   // s_emb [8][8][8]

__device__ __forceinline__ float sigm(float x) { return 1.0f / (1.0f + __expf(-x)); }
__device__ __forceinline__ float tanh_fast(float x) {
  x = fminf(15.0f, fmaxf(-15.0f, x));
  float e = __expf(2.0f * x);
  return (e - 1.0f) / (e + 1.0f);
}
__device__ __forceinline__ float leaky(float x) { return x >= 0.0f ? x : 0.01f * x; }

template <int N4>
__device__ __forceinline__ float dotv2(const float* __restrict__ w, const float* h) {
  const float4* w4 = reinterpret_cast<const float4*>(w);
  const float4* h4 = reinterpret_cast<const float4*>(h);
  float a0 = 0.0f, a1 = 0.0f;
#pragma unroll
  for (int i = 0; i < N4; i += 2) {
    float4 x0 = w4[i], y0 = h4[i];
    float4 x1 = w4[i + 1], y1 = h4[i + 1];
    a0 = fmaf(x0.x, y0.x, a0); a0 = fmaf(x0.y, y0.y, a0);
    a0 = fmaf(x0.z, y0.z, a0); a0 = fmaf(x0.w, y0.w, a0);
    a1 = fmaf(x1.x, y1.x, a1); a1 = fmaf(x1.y, y1.y, a1);
    a1 = fmaf(x1.z, y1.z, a1); a1 = fmaf(x1.w, y1.w, a1);
  }
  return a0 + a1;
}

template <int N4>
__device__ __forceinline__ float dotv4(const float* __restrict__ w, const float* h) {
  const float4* w4 = reinterpret_cast<const float4*>(w);
  const float4* h4 = reinterpret_cast<const float4*>(h);
  float a0 = 0.0f, a1 = 0.0f, a2 = 0.0f, a3 = 0.0f;
#pragma unroll
  for (int i = 0; i < N4; i += 4) {
    float4 x0 = w4[i], y0 = h4[i];
    float4 x1 = w4[i + 1], y1 = h4[i + 1];
    float4 x2 = w4[i + 2], y2 = h4[i + 2];
    float4 x3 = w4[i + 3], y3 = h4[i + 3];
    a0 = fmaf(x0.x, y0.x, a0); a0 = fmaf(x0.y, y0.y, a0);
    a0 = fmaf(x0.z, y0.z, a0); a0 = fmaf(x0.w, y0.w, a0);
    a1 = fmaf(x1.x, y1.x, a1); a1 = fmaf(x1.y, y1.y, a1);
    a1 = fmaf(x1.z, y1.z, a1); a1 = fmaf(x1.w, y1.w, a1);
    a2 = fmaf(x2.x, y2.x, a2); a2 = fmaf(x2.y, y2.y, a2);
    a2 = fmaf(x2.z, y2.z, a2); a2 = fmaf(x2.w, y2.w, a2);
    a3 = fmaf(x3.x, y3.x, a3); a3 = fmaf(x3.y, y3.y, a3);
    a3 = fmaf(x3.z, y3.z, a3); a3 = fmaf(x3.w, y3.w, a3);
  }
  return (a0 + a1) + (a2 + a3);
}

// dual-stream dot: one weight row, two activation streams (w loaded once).
template <int N4>
__device__ __forceinline__ void dot2_dual(const float* __restrict__ w,
                                          const float* hA, const float* hB,
                                          float& ra, float& rb) {
  const float4* w4 = reinterpret_cast<const float4*>(w);
  const float4* a4 = reinterpret_cast<const float4*>(hA);
  const float4* b4 = reinterpret_cast<const float4*>(hB);
  float a0 = 0.0f, a1 = 0.0f, b0 = 0.0f, b1 = 0.0f;
#pragma unroll
  for (int i = 0; i < N4; i += 2) {
    float4 w0 = w4[i], w1 = w4[i + 1];
    float4 x0 = a4[i], x1 = a4[i + 1];
    float4 y0 = b4[i], y1 = b4[i + 1];
    a0 = fmaf(w0.x, x0.x, a0); a0 = fmaf(w0.y, x0.y, a0);
    a0 = fmaf(w0.z, x0.z, a0); a0 = fmaf(w0.w, x0.w, a0);
    a1 = fmaf(w1.x, x1.x, a1); a1 = fmaf(w1.y, x1.y, a1);
    a1 = fmaf(w1.z, x1.z, a1); a1 = fmaf(w1.w, x1.w, a1);
    b0 = fmaf(w0.x, y0.x, b0); b0 = fmaf(w0.y, y0.y, b0);
    b0 = fmaf(w0.z, y0.z, b0); b0 = fmaf(w0.w, y0.w, b0);
    b1 = fmaf(w1.x, y1.x, b1); b1 = fmaf(w1.y, y1.y, b1);
    b1 = fmaf(w1.z, y1.z, b1); b1 = fmaf(w1.w, y1.w, b1);
  }
  ra = a0 + a1;
  rb = b0 + b1;
}

// ---- weight loaders ----
__device__ __forceinline__ void load_gates_w(
    const float* __restrict__ wih, const float* __restrict__ bih,
    int lane, int rowB, float4 WA[6], float4 WB[6], float& bA, float& bB) {
  const float4* wa = reinterpret_cast<const float4*>(wih + (size_t)lane * 24);
  const float4* wb = reinterpret_cast<const float4*>(wih + (size_t)rowB * 24);
#pragma unroll
  for (int i = 0; i < 6; ++i) { WA[i] = wa[i]; WB[i] = wb[i]; }
  bA = bih[lane]; bB = bih[rowB];
}

__device__ __forceinline__ void load_rec_w(
    const float* __restrict__ whh, const float* __restrict__ bhh, int jq,
    float4 Wr[6], float4 Wz[6], float4 Wn[6], float& bR, float& bZ, float& bN) {
  const float4* wr = reinterpret_cast<const float4*>(whh + jq * 24);
  const float4* wz = reinterpret_cast<const float4*>(whh + (24 + jq) * 24);
  const float4* wn = reinterpret_cast<const float4*>(whh + (48 + jq) * 24);
#pragma unroll
  for (int i = 0; i < 6; ++i) { Wr[i] = wr[i]; Wz[i] = wz[i]; Wn[i] = wn[i]; }
  bR = bhh[jq]; bZ = bhh[24 + jq]; bN = bhh[48 + jq];
}

// ---- gates: dual-stream, resident weights; t fully unrolled (L constexpr)
template <int L>
__device__ __forceinline__ void gates_dual(
    const float4 WA[6], const float4 WB[6], float bA, float bB,
    const float* g0, const float* g1, float* gi0, float* gi1, int lane) {
#pragma unroll
  for (int t = 0; t < L; ++t) {
    const float4* p4 = reinterpret_cast<const float4*>(g0 + t * 24);
    const float4* q4 = reinterpret_cast<const float4*>(g1 + t * 24);
    float a0 = bA, a1 = bA, c0 = bB, c1 = bB;
#pragma unroll
    for (int i = 0; i < 6; ++i) {
      float4 p = p4[i], q = q4[i], A = WA[i], Bv = WB[i];
      a0 = fmaf(A.x, p.x, a0); a0 = fmaf(A.y, p.y, a0);
      a0 = fmaf(A.z, p.z, a0); a0 = fmaf(A.w, p.w, a0);
      a1 = fmaf(A.x, q.x, a1); a1 = fmaf(A.y, q.y, a1);
      a1 = fmaf(A.z, q.z, a1); a1 = fmaf(A.w, q.w, a1);
      c0 = fmaf(Bv.x, p.x, c0); c0 = fmaf(Bv.y, p.y, c0);
      c0 = fmaf(Bv.z, p.z, c0); c0 = fmaf(Bv.w, p.w, c0);
      c1 = fmaf(Bv.x, q.x, c1); c1 = fmaf(Bv.y, q.y, c1);
      c1 = fmaf(Bv.z, q.z, c1); c1 = fmaf(Bv.w, q.w, c1);
    }
    gi0[t * 72 + lane] = a0;
    gi1[t * 72 + lane] = a1;
    if (lane < 8) {
      gi0[t * 72 + 64 + lane] = c0;
      gi1[t * 72 + 64 + lane] = c1;
    }
  }
}

// ---- GRU recurrence: group-parallel (lanes 0-23 = s0, 32-55 = s1),
// t fully unrolled (L constexpr); h round-trip is the only carried dep.
template <int L>
__device__ __forceinline__ void rec_grp(
    const float4 Wr[6], const float4 Wz[6], const float4 Wn[6],
    float bR, float bZ, float bN, float* sb, int jm, int jq) {
  if (jm < 24) sb[OHID + jm] = 0.0f;
  int cur = 0;
#pragma unroll
  for (int t = 0; t < L; ++t) {
    const float4* hp = reinterpret_cast<const float4*>(sb + OHID + cur * 24);
    float gr = bR, gz = bZ, gn = bN;
#pragma unroll
    for (int i = 0; i < 6; ++i) {
      float4 hh = hp[i];
      gr = fmaf(Wr[i].x, hh.x, gr); gr = fmaf(Wr[i].y, hh.y, gr);
      gr = fmaf(Wr[i].z, hh.z, gr); gr = fmaf(Wr[i].w, hh.w, gr);
      gz = fmaf(Wz[i].x, hh.x, gz); gz = fmaf(Wz[i].y, hh.y, gz);
      gz = fmaf(Wz[i].z, hh.z, gz); gz = fmaf(Wz[i].w, hh.w, gz);
      gn = fmaf(Wn[i].x, hh.x, gn); gn = fmaf(Wn[i].y, hh.y, gn);
      gn = fmaf(Wn[i].z, hh.z, gn); gn = fmaf(Wn[i].w, hh.w, gn);
    }
    const float* gi = sb + OGI + t * 72;
    float r   = sigm(gi[jq] + gr);
    float zg  = sigm(gi[24 + jq] + gz);
    float nn2 = tanh_fast(gi[48 + jq] + r * gn);
    float hold = sb[OHID + cur * 24 + jq];
    float hnew = fmaf(zg, hold - nn2, nn2);  // (1-z)*n + z*h
    if (jm < 24) {
      sb[OHID + (cur ^ 1) * 24 + jm] = hnew;
      sb[OY + t * 24 + jm] = hnew;
    }
    cur ^= 1;
  }
}

struct Params {
  const float *z, *cond_w1, *cond_b1, *cond_w2, *cond_b2;
  const float *proj_w, *proj_b, *gpw, *gpb;
  const float *gru_wih, *gru_whh, *gru_bih, *gru_bhh;
  const float *cm_w1, *cm_b1, *cm_w2, *cm_b2, *cm_w3, *cm_b3;
  float* out;
  int Btot, T;
};

// one idx-iteration (all 8 nodes) with L = idx+1 compile-time.
template <int L>
__device__ __noinline__ void run_iter(
    const Params& P, float* lds, int lane, int jm, int grp, int jq, int rowB,
    int bs, bool writeOK) {
  constexpr int idx = L - 1;
  float* Ls0 = lds;
  float* Ls1 = lds + SS;
  float* myb = lds + grp * SS;

#pragma unroll 1
  for (int n = 0; n < 8; ++n) {
    const float* wih0 = P.gru_wih + (size_t)(n * 2) * 1728;
    const float* wih1 = wih0 + 1728;
    const float* whh0 = P.gru_whh + (size_t)(n * 2) * 1728;
    const float* whh1 = whh0 + 1728;
    const float* bih0 = P.gru_bih + (n * 2) * 72;
    const float* bih1 = bih0 + 72;
    const float* bhh0 = P.gru_bhh + (n * 2) * 72;
    const float* bhh1 = bhh0 + 72;

    // prefetch gates-L0 weights (used 3 stages later)
    float4 WA[6], WB[6]; float bA, bB;
    load_gates_w(wih0, bih0, lane, rowB, WA, WB, bA, bB);

    // ---- phase A (group-parallel): s_x = [z | emb_self | emb_pred]
    {
      const float4* z4 = reinterpret_cast<const float4*>(
          P.z + ((size_t)n * P.Btot + bs) * 256);
      float4* x4 = reinterpret_cast<float4*>(myb + OX);
      for (int it = jm; it < L * 8; it += 32) {
        int t = it >> 3, q = it & 7;
        x4[t * 12 + q] = z4[t * 8 + q];
      }
      for (int it = jm; it < L * 16; it += 32) {
        int t = it >> 4, c = it & 15;
        float v = 0.0f;
        if (c < 8) {
          if (t < idx) v = myb[OEMB + n * 64 + t * 8 + c];
        } else {
          if (n > 0 && idx > 0) v = myb[OEMB + (n - 1) * 64 + t * 8 + (c - 8)];
        }
        myb[OX + t * 48 + 32 + c] = v;
      }
    }
    SYNC();
    // ---- proj -> leaky (dual-stream)
    for (int it = lane; it < L * 24; it += NT) {
      int t = it / 24, j = it - t * 24;
      float ra, rb;
      dot2_dual<12>(P.proj_w + (size_t)(n * 24 + j) * 48,
                    Ls0 + OX + t * 48, Ls1 + OX + t * 48, ra, rb);
      float pb = P.proj_b[n * 24 + j];
      Ls0[OH + t * 24 + j] = leaky(pb + ra);
      Ls1[OH + t * 24 + j] = leaky(pb + rb);
    }
    SYNC();
    // ---- gru_proj (dual-stream)
    for (int it = lane; it < L * 24; it += NT) {
      int t = it / 24, j = it - t * 24;
      float ra, rb;
      dot2_dual<6>(P.gpw + j * 24, Ls0 + OH + t * 24, Ls1 + OH + t * 24, ra, rb);
      float gb = P.gpb[j];
      Ls0[OG + t * 24 + j] = gb + ra;
      Ls1[OG + t * 24 + j] = gb + rb;
    }
    SYNC();
    // prefetch rec-L0 weights (in flight during gates L0)
    float4 Wr[6], Wz[6], Wn[6]; float bR, bZ, bN;
    load_rec_w(whh0, bhh0, jq, Wr, Wz, Wn, bR, bZ, bN);
    // ---- gates L0 (dual)
    gates_dual<L>(WA, WB, bA, bB, Ls0 + OG, Ls1 + OG, Ls0 + OGI, Ls1 + OGI, lane);
    SYNC();
    // prefetch gates-L1 weights (in flight during rec L0)
    load_gates_w(wih1, bih1, lane, rowB, WA, WB, bA, bB);
    // ---- rec L0 (group-parallel)
    rec_grp<L>(Wr, Wz, Wn, bR, bZ, bN, myb, jm, jq);
    SYNC();
    // prefetch rec-L1 weights (in flight during gates L1)
    load_rec_w(whh1, bhh1, jq, Wr, Wz, Wn, bR, bZ, bN);
    // ---- gates L1 (dual, src = s_y)
    gates_dual<L>(WA, WB, bA, bB, Ls0 + OY, Ls1 + OY, Ls0 + OGI, Ls1 + OGI, lane);
    SYNC();
    // prefetch cm1 row (in flight during rec L1)
    float4 C1[6];
    {
      const float4* p = reinterpret_cast<const float4*>(
          P.cm_w1 + (size_t)(n * 64 + lane) * 24);
#pragma unroll
      for (int i = 0; i < 6; ++i) C1[i] = p[i];
    }
    const float c1b = P.cm_b1[n * 64 + lane];
    // ---- rec L1 (group-parallel)
    rec_grp<L>(Wr, Wz, Wn, bR, bZ, bN, myb, jm, jq);
    SYNC();
    // ---- cm1 (dual, resident C1; 2 sub-accs per sample)
#pragma unroll
    for (int t = 0; t < L; ++t) {
      const float4* p4 = reinterpret_cast<const float4*>(Ls0 + OY + t * 24);
      const float4* q4 = reinterpret_cast<const float4*>(Ls1 + OY + t * 24);
      float a0 = c1b, a1 = 0.0f, d0 = c1b, d1 = 0.0f;
#pragma unroll
      for (int i = 0; i < 6; i += 2) {
        float4 w0 = C1[i], w1 = C1[i + 1];
        float4 p0 = p4[i], p1 = p4[i + 1], q0 = q4[i], q1 = q4[i + 1];
        a0 = fmaf(w0.x, p0.x, a0); a0 = fmaf(w0.y, p0.y, a0);
        a0 = fmaf(w0.z, p0.z, a0); a0 = fmaf(w0.w, p0.w, a0);
        a1 = fmaf(w1.x, p1.x, a1); a1 = fmaf(w1.y, p1.y, a1);
        a1 = fmaf(w1.z, p1.z, a1); a1 = fmaf(w1.w, p1.w, a1);
        d0 = fmaf(w0.x, q0.x, d0); d0 = fmaf(w0.y, q0.y, d0);
        d0 = fmaf(w0.z, q0.z, d0); d0 = fmaf(w0.w, q0.w, d0);
        d1 = fmaf(w1.x, q1.x, d1); d1 = fmaf(w1.y, q1.y, d1);
        d1 = fmaf(w1.z, q1.z, d1); d1 = fmaf(w1.w, q1.w, d1);
      }
      Ls0[OD1 + t * 68 + lane] = fmaxf(a0 + a1, 0.0f);
      Ls1[OD1 + t * 68 + lane] = fmaxf(d0 + d1, 0.0f);
    }
    SYNC();
    // ---- cm2 (dual, C2 JIT; 2 sub-accs per sample)
    {
      float4 C2[16];
      const float4* p2 = reinterpret_cast<const float4*>(
          P.cm_w2 + (size_t)(n * 64 + lane) * 64);
#pragma unroll
      for (int i = 0; i < 16; ++i) C2[i] = p2[i];
      const float c2b = P.cm_b2[n * 64 + lane];
#pragma unroll
      for (int t = 0; t < L; ++t) {
        const float4* p4 = reinterpret_cast<const float4*>(Ls0 + OD1 + t * 68);
        const float4* q4 = reinterpret_cast<const float4*>(Ls1 + OD1 + t * 68);
        float a0 = c2b, a1 = 0.0f, d0 = c2b, d1 = 0.0f;
#pragma unroll
        for (int i = 0; i < 16; i += 2) {
          float4 w0 = C2[i], w1 = C2[i + 1];
          float4 p0 = p4[i], p1 = p4[i + 1], q0 = q4[i], q1 = q4[i + 1];
          a0 = fmaf(w0.x, p0.x, a0); a0 = fmaf(w0.y, p0.y, a0);
          a0 = fmaf(w0.z, p0.z, a0); a0 = fmaf(w0.w, p0.w, a0);
          a1 = fmaf(w1.x, p1.x, a1); a1 = fmaf(w1.y, p1.y, a1);
          a1 = fmaf(w1.z, p1.z, a1); a1 = fmaf(w1.w, p1.w, a1);
          d0 = fmaf(w0.x, q0.x, d0); d0 = fmaf(w0.y, q0.y, d0);
          d0 = fmaf(w0.z, q0.z, d0); d0 = fmaf(w0.w, q0.w, d0);
          d1 = fmaf(w1.x, q1.x, d1); d1 = fmaf(w1.y, q1.y, d1);
          d1 = fmaf(w1.z, q1.z, d1); d1 = fmaf(w1.w, q1.w, d1);
        }
        Ls0[OD2 + t * 68 + lane] = fmaxf(a0 + a1, 0.0f);
        Ls1[OD2 + t * 68 + lane] = fmaxf(d0 + d1, 0.0f);
      }
    }
    SYNC();
    // ---- cm3 (group-parallel) -> decoded row + emit
    if (jm < L) {
      int t = jm;
      float dv = P.cm_b3[n] + dotv4<16>(P.cm_w3 + n * 64, myb + OD2 + t * 68);
      myb[ODD + t] = dv;
      if (t == idx && writeOK)
        P.out[((size_t)bs * P.T + idx) * 8 + n] = dv;
    }
    SYNC();
    // ---- cond-net once per decoded row -> s_emb[n] (group-parallel)
    for (int it = jm; it < L * 32; it += 32) {
      int t = it >> 5, k = it & 31;
      myb[OCH + t * 36 + k] =
          fmaxf(fmaf(myb[ODD + t], P.cond_w1[n * 32 + k], P.cond_b1[n * 32 + k]),
                0.0f);
    }
    SYNC();
    for (int it = jm; it < L * 8; it += 32) {
      int t = it >> 3, c = it & 7;
      myb[OEMB + n * 64 + t * 8 + c] =
          P.cond_b2[n * 8 + c] +
          dotv2<8>(P.cond_w2 + (size_t)(n * 8 + c) * 32, myb + OCH + t * 36);
    }
    SYNC();
  }
}

__global__ __launch_bounds__(NT, 1) void tcm_kernel(
    const float* __restrict__ z,
    const float* __restrict__ cond_w1, const float* __restrict__ cond_b1,
    const float* __restrict__ cond_w2, const float* __restrict__ cond_b2,
    const float* __restrict__ proj_w, const float* __restrict__ proj_b,
    const float* __restrict__ gpw, const float* __restrict__ gpb,
    const float* __restrict__ gru_wih, const float* __restrict__ gru_whh,
    const float* __restrict__ gru_bih, const float* __restrict__ gru_bhh,
    const float* __restrict__ cm_w1, const float* __restrict__ cm_b1,
    const float* __restrict__ cm_w2, const float* __restrict__ cm_b2,
    const float* __restrict__ cm_w3, const float* __restrict__ cm_b3,
    const int* __restrict__ endw,
    float* __restrict__ out, int Btot) {
  __shared__ __align__(16) float lds[2 * SS];

  const int lane = threadIdx.x;
  const int jm   = lane & 31;
  const int grp  = lane >> 5;
  const int jq   = jm < 24 ? jm : 0;
  const int rowB = 64 + (lane & 7);
  const int T = endw[0];

  const int b0 = 2 * blockIdx.x;
  const int b1 = b0 + 1;
  const bool b1ok = (b1 < Btot);
  const int b1c = b1ok ? b1 : (Btot - 1);
  const int bs = grp ? b1c : b0;
  const bool writeOK = (grp == 0) || b1ok;

  Params P{z, cond_w1, cond_b1, cond_w2, cond_b2, proj_w, proj_b, gpw, gpb,
           gru_wih, gru_whh, gru_bih, gru_bhh, cm_w1, cm_b1, cm_w2, cm_b2,
           cm_w3, cm_b3, out, Btot, T};

#pragma unroll 1
  for (int idx = 0; idx < T; ++idx) {
    switch (idx) {
      case 0: run_iter<1>(P, lds, lane, jm, grp, jq, rowB, bs, writeOK); break;
      case 1: run_iter<2>(P, lds, lane, jm, grp, jq, rowB, bs, writeOK); break;
      case 2: run_iter<3>(P, lds, lane, jm, grp, jq, rowB, bs, writeOK); break;
      case 3: run_iter<4>(P, lds, lane, jm, grp, jq, rowB, bs, writeOK); break;
      case 4: run_iter<5>(P, lds, lane, jm, grp, jq, rowB, bs, writeOK); break;
      case 5: run_iter<6>(P, lds, lane, jm, grp, jq, rowB, bs, writeOK); break;
      case 6: run_iter<7>(P, lds, lane, jm, grp, jq, rowB, bs, writeOK); break;
      case 7: run_iter<8>(P, lds, lane, jm, grp, jq, rowB, bs, writeOK); break;
      default: break;  // T <= 8 per problem spec (LDS sized for L <= 8)
    }
  }
}

extern "C" void kernel_launch(void* const* d_in, const int* in_sizes, int n_in,
                              void* d_out, int out_size, void* d_ws, size_t ws_size,
                              hipStream_t stream) {
  const float* z       = (const float*)d_in[0];
  const float* cond_w1 = (const float*)d_in[1];
  const float* cond_b1 = (const float*)d_in[2];
  const float* cond_w2 = (const float*)d_in[3];
  const float* cond_b2 = (const float*)d_in[4];
  const float* proj_w  = (const float*)d_in[5];
  const float* proj_b  = (const float*)d_in[6];
  const float* gpw     = (const float*)d_in[7];
  const float* gpb     = (const float*)d_in[8];
  const float* gru_wih = (const float*)d_in[9];
  const float* gru_whh = (const float*)d_in[10];
  const float* gru_bih = (const float*)d_in[11];
  const float* gru_bhh = (const float*)d_in[12];
  const float* cm_w1   = (const float*)d_in[13];
  const float* cm_b1   = (const float*)d_in[14];
  const float* cm_w2   = (const float*)d_in[15];
  const float* cm_b2   = (const float*)d_in[16];
  const float* cm_w3   = (const float*)d_in[17];
  const float* cm_b3   = (const float*)d_in[18];
  const int*   endw    = (const int*)d_in[19];
  float* out = (float*)d_out;

  int Btot = in_sizes[0] / (8 * 8 * 32);  // z: [8, B, 8, 32]
  int nblocks = (Btot + 1) / 2;

  tcm_kernel<<<nblocks, NT, 0, stream>>>(
      z, cond_w1, cond_b1, cond_w2, cond_b2, proj_w, proj_b, gpw, gpb,
      gru_wih, gru_whh, gru_bih, gru_bhh, cm_w1, cm_b1, cm_w2, cm_b2,
      cm_w3, cm_b3, endw, out, Btot);
}

// Round 13
// 1123.854 us; speedup vs baseline: 1.0352x; 1.0352x over previous
//
#include <hip/hip_runtime.h>

// TemporalCausalMaps on MI355X (gfx950), round 16.
// Base = round 8 (best verified: 1025.7us, VGPR 124, no spills, 1 wave/block,
// lgkm-only SYNC, cross-stage weight prefetch, cond-once -> s_emb).
// Single focused change: GRU recurrence h kept IN REGISTERS, broadcast via
// v_readlane (VALU) instead of the per-step LDS write->ds_read_b128 round
// trip (~100cyc RAW on the serial critical path, 576 steps/sample).
//  - lane j (<24) owns h[j]; 24 readlanes/step feed full 24-wide gate dots
//    as SGPR operands (1 sgpr/VALU op is legal).
//  - no half-split, no shfl_xor combine, no s_hid traffic, full bias.
//  - rec weights now full rows (72 VGPR); peak live ~170 < 256 cap (64,2).

#define NT 64
#define SYNC() asm volatile("s_waitcnt lgkmcnt(0)" ::: "memory")

__device__ __forceinline__ float sigm(float x) { return 1.0f / (1.0f + __expf(-x)); }
__device__ __forceinline__ float tanh_fast(float x) {
  x = fminf(15.0f, fmaxf(-15.0f, x));
  float e = __expf(2.0f * x);
  return (e - 1.0f) / (e + 1.0f);
}
__device__ __forceinline__ float leaky(float x) { return x >= 0.0f ? x : 0.01f * x; }
__device__ __forceinline__ float readlane_f(float v, int k) {
  return __uint_as_float(__builtin_amdgcn_readlane(__float_as_uint(v), k));
}

template <int N4>
__device__ __forceinline__ float dotv2(const float* __restrict__ w, const float* h) {
  const float4* w4 = reinterpret_cast<const float4*>(w);
  const float4* h4 = reinterpret_cast<const float4*>(h);
  float a0 = 0.0f, a1 = 0.0f;
#pragma unroll
  for (int i = 0; i < N4; i += 2) {
    float4 x0 = w4[i], y0 = h4[i];
    float4 x1 = w4[i + 1], y1 = h4[i + 1];
    a0 = fmaf(x0.x, y0.x, a0); a0 = fmaf(x0.y, y0.y, a0);
    a0 = fmaf(x0.z, y0.z, a0); a0 = fmaf(x0.w, y0.w, a0);
    a1 = fmaf(x1.x, y1.x, a1); a1 = fmaf(x1.y, y1.y, a1);
    a1 = fmaf(x1.z, y1.z, a1); a1 = fmaf(x1.w, y1.w, a1);
  }
  return a0 + a1;
}

template <int N4>
__device__ __forceinline__ float dotv4(const float* __restrict__ w, const float* h) {
  const float4* w4 = reinterpret_cast<const float4*>(w);
  const float4* h4 = reinterpret_cast<const float4*>(h);
  float a0 = 0.0f, a1 = 0.0f, a2 = 0.0f, a3 = 0.0f;
#pragma unroll
  for (int i = 0; i < N4; i += 4) {
    float4 x0 = w4[i], y0 = h4[i];
    float4 x1 = w4[i + 1], y1 = h4[i + 1];
    float4 x2 = w4[i + 2], y2 = h4[i + 2];
    float4 x3 = w4[i + 3], y3 = h4[i + 3];
    a0 = fmaf(x0.x, y0.x, a0); a0 = fmaf(x0.y, y0.y, a0);
    a0 = fmaf(x0.z, y0.z, a0); a0 = fmaf(x0.w, y0.w, a0);
    a1 = fmaf(x1.x, y1.x, a1); a1 = fmaf(x1.y, y1.y, a1);
    a1 = fmaf(x1.z, y1.z, a1); a1 = fmaf(x1.w, y1.w, a1);
    a2 = fmaf(x2.x, y2.x, a2); a2 = fmaf(x2.y, y2.y, a2);
    a2 = fmaf(x2.z, y2.z, a2); a2 = fmaf(x2.w, y2.w, a2);
    a3 = fmaf(x3.x, y3.x, a3); a3 = fmaf(x3.y, y3.y, a3);
    a3 = fmaf(x3.z, y3.z, a3); a3 = fmaf(x3.w, y3.w, a3);
  }
  return (a0 + a1) + (a2 + a3);
}

// ---- weight loaders (prefetch points) ----
__device__ __forceinline__ void load_gates_w(
    const float* __restrict__ wih, const float* __restrict__ bih,
    int lane, int rowB, float4 WA[6], float4 WB[6], float& bA, float& bB) {
  const float4* wa = reinterpret_cast<const float4*>(wih + (size_t)lane * 24);
  const float4* wb = reinterpret_cast<const float4*>(wih + (size_t)rowB * 24);
#pragma unroll
  for (int i = 0; i < 6; ++i) { WA[i] = wa[i]; WB[i] = wb[i]; }
  bA = bih[lane]; bB = bih[rowB];
}

// full 24-wide rec rows, unpacked to scalars (constexpr-indexable).
__device__ __forceinline__ void load_rec_w_full(
    const float* __restrict__ whh, const float* __restrict__ bhh, int jq,
    float Wr[24], float Wz[24], float Wn[24], float& bR, float& bZ, float& bN) {
  const float4* wr4 = reinterpret_cast<const float4*>(whh + jq * 24);
  const float4* wz4 = reinterpret_cast<const float4*>(whh + (24 + jq) * 24);
  const float4* wn4 = reinterpret_cast<const float4*>(whh + (48 + jq) * 24);
#pragma unroll
  for (int i = 0; i < 6; ++i) {
    float4 a = wr4[i], b = wz4[i], c = wn4[i];
    Wr[4 * i] = a.x; Wr[4 * i + 1] = a.y; Wr[4 * i + 2] = a.z; Wr[4 * i + 3] = a.w;
    Wz[4 * i] = b.x; Wz[4 * i + 1] = b.y; Wz[4 * i + 2] = b.z; Wz[4 * i + 3] = b.w;
    Wn[4 * i] = c.x; Wn[4 * i + 1] = c.y; Wn[4 * i + 2] = c.z; Wn[4 * i + 3] = c.w;
  }
  bR = bhh[jq]; bZ = bhh[24 + jq]; bN = bhh[48 + jq];
}

// ---- gates: lane = row, t-pair ILP (unchanged from r8) ----
__device__ __forceinline__ void gates_comp(
    const float4 WA[6], const float4 WB[6], float bA, float bB,
    const float* srcp, float* s_gi, int L, int lane) {
  int t = 0;
#pragma unroll 1
  for (; t + 1 < L; t += 2) {
    const float4* h0 = reinterpret_cast<const float4*>(srcp + t * 24);
    const float4* h1 = reinterpret_cast<const float4*>(srcp + t * 24 + 24);
    float a0 = bA, a1 = bA, c0 = bB, c1 = bB;
#pragma unroll
    for (int i = 0; i < 6; ++i) {
      float4 p = h0[i], q = h1[i], A = WA[i], Bv = WB[i];
      a0 = fmaf(A.x, p.x, a0); a0 = fmaf(A.y, p.y, a0);
      a0 = fmaf(A.z, p.z, a0); a0 = fmaf(A.w, p.w, a0);
      a1 = fmaf(A.x, q.x, a1); a1 = fmaf(A.y, q.y, a1);
      a1 = fmaf(A.z, q.z, a1); a1 = fmaf(A.w, q.w, a1);
      c0 = fmaf(Bv.x, p.x, c0); c0 = fmaf(Bv.y, p.y, c0);
      c0 = fmaf(Bv.z, p.z, c0); c0 = fmaf(Bv.w, p.w, c0);
      c1 = fmaf(Bv.x, q.x, c1); c1 = fmaf(Bv.y, q.y, c1);
      c1 = fmaf(Bv.z, q.z, c1); c1 = fmaf(Bv.w, q.w, c1);
    }
    s_gi[t * 72 + lane] = a0;
    s_gi[t * 72 + 72 + lane] = a1;
    if (lane < 8) {
      s_gi[t * 72 + 64 + lane] = c0;
      s_gi[t * 72 + 136 + lane] = c1;
    }
  }
  if (t < L) {
    const float4* h0 = reinterpret_cast<const float4*>(srcp + t * 24);
    float a0 = bA, c0 = bB;
#pragma unroll
    for (int i = 0; i < 6; ++i) {
      float4 p = h0[i], A = WA[i], Bv = WB[i];
      a0 = fmaf(A.x, p.x, a0); a0 = fmaf(A.y, p.y, a0);
      a0 = fmaf(A.z, p.z, a0); a0 = fmaf(A.w, p.w, a0);
      c0 = fmaf(Bv.x, p.x, c0); c0 = fmaf(Bv.y, p.y, c0);
      c0 = fmaf(Bv.z, p.z, c0); c0 = fmaf(Bv.w, p.w, c0);
    }
    s_gi[t * 72 + lane] = a0;
    if (lane < 8) s_gi[t * 72 + 64 + lane] = c0;
  }
}

// ---- GRU recurrence: h in registers, broadcast via v_readlane.
// Lane j (<24) owns h[j]; lanes >=24 compute a replica of row 0 (jq=0),
// never read. Per step: 3 scalar gi LDS loads + 24 readlanes + 72 FMA;
// no LDS write->read round trip on the serial chain.
__device__ __forceinline__ void rec_comp_rl(
    const float Wr[24], const float Wz[24], const float Wn[24],
    float bR, float bZ, float bN,
    const float* s_gi, float* s_y, int L, int lane, int jq) {
  float h = 0.0f;
#pragma unroll 1
  for (int t = 0; t < L; ++t) {
    const float* gi = s_gi + t * 72;
    float g0 = gi[jq], g1 = gi[24 + jq], g2 = gi[48 + jq];
    float gr = bR, gz = bZ, gn = bN;
#pragma unroll
    for (int k = 0; k < 24; ++k) {
      float hk = readlane_f(h, k);
      gr = fmaf(Wr[k], hk, gr);
      gz = fmaf(Wz[k], hk, gz);
      gn = fmaf(Wn[k], hk, gn);
    }
    float r   = sigm(g0 + gr);
    float zg  = sigm(g1 + gz);
    float nn2 = tanh_fast(g2 + r * gn);
    h = fmaf(zg, h - nn2, nn2);  // (1-z)*n + z*h, h stays in register
    if (lane < 24) s_y[t * 24 + lane] = h;
  }
}

// LDS layout (floats). Total 3488 floats = 13952 B.
//  s_x   [8][48] @0      s_h  [8][24] @384    s_g   [8][24] @576
//  s_gi  [8][72] @768    s_y  [8][24] @1344   (s_hid slot unused) @1536
//  s_d1  [8][68] @1584   s_d2 [8][68] @2128   s_dd  [16]    @2672
//  s_ch  [8][36] @2688   s_emb[8][8][8] @2976
__global__ __launch_bounds__(NT, 2) void tcm_kernel(
    const float* __restrict__ z,
    const float* __restrict__ cond_w1, const float* __restrict__ cond_b1,
    const float* __restrict__ cond_w2, const float* __restrict__ cond_b2,
    const float* __restrict__ proj_w, const float* __restrict__ proj_b,
    const float* __restrict__ gpw, const float* __restrict__ gpb,
    const float* __restrict__ gru_wih, const float* __restrict__ gru_whh,
    const float* __restrict__ gru_bih, const float* __restrict__ gru_bhh,
    const float* __restrict__ cm_w1, const float* __restrict__ cm_b1,
    const float* __restrict__ cm_w2, const float* __restrict__ cm_b2,
    const float* __restrict__ cm_w3, const float* __restrict__ cm_b3,
    const int* __restrict__ endw,
    float* __restrict__ out, int Btot) {
  __shared__ __align__(16) float lds[3488];
  float* s_x   = lds;
  float* s_h   = lds + 384;
  float* s_g   = lds + 576;
  float* s_gi  = lds + 768;
  float* s_y   = lds + 1344;
  float* s_d1  = lds + 1584;   // stride 68
  float* s_d2  = lds + 2128;   // stride 68
  float* s_dd  = lds + 2672;
  float* s_ch  = lds + 2688;   // stride 36
  float* s_emb = lds + 2976;   // [n][t][c] = n*64 + t*8 + c

  const int lane = threadIdx.x;
  const int b = blockIdx.x;
  const int T = endw[0];
  const int jrec = lane < 24 ? lane : 0;   // rec row owned by this lane
  const int rowB = 64 + (lane & 7);

#pragma unroll 1
  for (int idx = 0; idx < T; ++idx) {
    const int L = idx + 1;
#pragma unroll 1
    for (int n = 0; n < 8; ++n) {
      const float* wih0 = gru_wih + (size_t)(n * 2) * 1728;
      const float* wih1 = wih0 + 1728;
      const float* whh0 = gru_whh + (size_t)(n * 2) * 1728;
      const float* whh1 = whh0 + 1728;
      const float* bih0 = gru_bih + (n * 2) * 72;
      const float* bih1 = bih0 + 72;
      const float* bhh0 = gru_bhh + (n * 2) * 72;
      const float* bhh1 = bhh0 + 72;

      // prefetch gates-L0 weights (used after proj/gproj)
      float4 WA[6], WB[6]; float bA, bB;
      load_gates_w(wih0, bih0, lane, rowB, WA, WB, bA, bB);

      // ---- phase A: s_x = [z | emb_self | emb_pred]
      if (lane < L * 8) {
        const float4* z4 = reinterpret_cast<const float4*>(
            z + ((size_t)n * Btot + b) * 8 * 32);
        int t = lane >> 3, q = lane & 7;
        reinterpret_cast<float4*>(s_x)[t * 12 + q] = z4[t * 8 + q];
      }
#pragma unroll 1
      for (int it = lane; it < L * 16; it += NT) {
        int t = it >> 4, c = it & 15;
        float v = 0.0f;
        if (c < 8) {
          if (t < idx) v = s_emb[n * 64 + t * 8 + c];
        } else {
          if (n > 0 && idx > 0) v = s_emb[(n - 1) * 64 + t * 8 + (c - 8)];
        }
        s_x[t * 48 + 32 + c] = v;
      }
      SYNC();
      // ---- proj -> leaky
#pragma unroll 1
      for (int it = lane; it < L * 24; it += NT) {
        int t = it / 24, j = it - t * 24;
        float acc = proj_b[n * 24 + j] +
                    dotv2<12>(proj_w + (size_t)(n * 24 + j) * 48, s_x + t * 48);
        s_h[t * 24 + j] = leaky(acc);
      }
      SYNC();
      // ---- gru_proj
#pragma unroll 1
      for (int it = lane; it < L * 24; it += NT) {
        int t = it / 24, j = it - t * 24;
        s_g[t * 24 + j] = gpb[j] + dotv2<6>(gpw + j * 24, s_h + t * 24);
      }
      SYNC();
      // prefetch rec-L0 weights (in flight during gates L0)
      float Wr[24], Wz[24], Wn[24]; float bR, bZ, bN;
      load_rec_w_full(whh0, bhh0, jrec, Wr, Wz, Wn, bR, bZ, bN);
      // ---- gates L0
      gates_comp(WA, WB, bA, bB, s_g, s_gi, L, lane);
      SYNC();
      // prefetch gates-L1 weights (in flight during rec L0)
      float4 WA1[6], WB1[6]; float bA1, bB1;
      load_gates_w(wih1, bih1, lane, rowB, WA1, WB1, bA1, bB1);
      // ---- rec L0 -> s_y (register-h, readlane broadcast)
      rec_comp_rl(Wr, Wz, Wn, bR, bZ, bN, s_gi, s_y, L, lane, jrec);
      SYNC();
      // prefetch rec-L1 weights (in flight during gates L1)
      load_rec_w_full(whh1, bhh1, jrec, Wr, Wz, Wn, bR, bZ, bN);
      // ---- gates L1
      gates_comp(WA1, WB1, bA1, bB1, s_y, s_gi, L, lane);
      SYNC();
      // prefetch cm1 row (in flight during rec L1)
      float4 C1[6];
      {
        const float4* p = reinterpret_cast<const float4*>(
            cm_w1 + (size_t)(n * 64 + lane) * 24);
#pragma unroll
        for (int i = 0; i < 6; ++i) C1[i] = p[i];
      }
      const float c1b = cm_b1[n * 64 + lane];
      // ---- rec L1 -> s_y
      rec_comp_rl(Wr, Wz, Wn, bR, bZ, bN, s_gi, s_y, L, lane, jrec);
      SYNC();
      // prefetch cm2 row (in flight during cm1)
      float4 C2[16];
      {
        const float4* p = reinterpret_cast<const float4*>(
            cm_w2 + (size_t)(n * 64 + lane) * 64);
#pragma unroll
        for (int i = 0; i < 16; ++i) C2[i] = p[i];
      }
      const float c2b = cm_b2[n * 64 + lane];
      // ---- cm1: lane = j, t-pairs
      {
        int t = 0;
#pragma unroll 1
        for (; t + 1 < L; t += 2) {
          const float4* y0 = reinterpret_cast<const float4*>(s_y + t * 24);
          const float4* y1 = reinterpret_cast<const float4*>(s_y + t * 24 + 24);
          float a0 = c1b, a1 = c1b;
#pragma unroll
          for (int i = 0; i < 6; ++i) {
            float4 pp = y0[i], q = y1[i], W = C1[i];
            a0 = fmaf(W.x, pp.x, a0); a0 = fmaf(W.y, pp.y, a0);
            a0 = fmaf(W.z, pp.z, a0); a0 = fmaf(W.w, pp.w, a0);
            a1 = fmaf(W.x, q.x, a1); a1 = fmaf(W.y, q.y, a1);
            a1 = fmaf(W.z, q.z, a1); a1 = fmaf(W.w, q.w, a1);
          }
          s_d1[t * 68 + lane] = fmaxf(a0, 0.0f);
          s_d1[t * 68 + 68 + lane] = fmaxf(a1, 0.0f);
        }
        if (t < L) {
          float acc = c1b;
          const float4* y0 = reinterpret_cast<const float4*>(s_y + t * 24);
#pragma unroll
          for (int i = 0; i < 6; ++i) {
            float4 pp = y0[i], W = C1[i];
            acc = fmaf(W.x, pp.x, acc); acc = fmaf(W.y, pp.y, acc);
            acc = fmaf(W.z, pp.z, acc); acc = fmaf(W.w, pp.w, acc);
          }
          s_d1[t * 68 + lane] = fmaxf(acc, 0.0f);
        }
      }
      SYNC();
      // ---- cm2: lane = j, t-pairs, 2 accs per t
      {
        int t = 0;
#pragma unroll 1
        for (; t + 1 < L; t += 2) {
          const float4* d0 = reinterpret_cast<const float4*>(s_d1 + t * 68);
          const float4* d1 = reinterpret_cast<const float4*>(s_d1 + t * 68 + 68);
          float a0 = c2b, a1 = 0.0f, c0 = c2b, c1 = 0.0f;
#pragma unroll
          for (int i = 0; i < 16; i += 2) {
            float4 W0 = C2[i], W1 = C2[i + 1];
            float4 p0 = d0[i], p1 = d0[i + 1], q0 = d1[i], q1 = d1[i + 1];
            a0 = fmaf(W0.x, p0.x, a0); a0 = fmaf(W0.y, p0.y, a0);
            a0 = fmaf(W0.z, p0.z, a0); a0 = fmaf(W0.w, p0.w, a0);
            a1 = fmaf(W1.x, p1.x, a1); a1 = fmaf(W1.y, p1.y, a1);
            a1 = fmaf(W1.z, p1.z, a1); a1 = fmaf(W1.w, p1.w, a1);
            c0 = fmaf(W0.x, q0.x, c0); c0 = fmaf(W0.y, q0.y, c0);
            c0 = fmaf(W0.z, q0.z, c0); c0 = fmaf(W0.w, q0.w, c0);
            c1 = fmaf(W1.x, q1.x, c1); c1 = fmaf(W1.y, q1.y, c1);
            c1 = fmaf(W1.z, q1.z, c1); c1 = fmaf(W1.w, q1.w, c1);
          }
          s_d2[t * 68 + lane] = fmaxf(a0 + a1, 0.0f);
          s_d2[t * 68 + 68 + lane] = fmaxf(c0 + c1, 0.0f);
        }
        if (t < L) {
          const float4* d0 = reinterpret_cast<const float4*>(s_d1 + t * 68);
          float a0 = c2b, a1 = 0.0f;
#pragma unroll
          for (int i = 0; i < 16; i += 2) {
            float4 W0 = C2[i], W1 = C2[i + 1];
            float4 p0 = d0[i], p1 = d0[i + 1];
            a0 = fmaf(W0.x, p0.x, a0); a0 = fmaf(W0.y, p0.y, a0);
            a0 = fmaf(W0.z, p0.z, a0); a0 = fmaf(W0.w, p0.w, a0);
            a1 = fmaf(W1.x, p1.x, a1); a1 = fmaf(W1.y, p1.y, a1);
            a1 = fmaf(W1.z, p1.z, a1); a1 = fmaf(W1.w, p1.w, a1);
          }
          s_d2[t * 68 + lane] = fmaxf(a0 + a1, 0.0f);
        }
      }
      SYNC();
      // ---- cm3 -> decoded row + emit
      if (lane < L) {
        int t = lane;
        float dv = cm_b3[n] + dotv4<16>(cm_w3 + n * 64, s_d2 + t * 68);
        s_dd[t] = dv;
        if (t == idx)
          out[((size_t)b * T + idx) * 8 + n] = dv;
      }
      SYNC();
      // ---- cond-net ONCE per decoded row -> s_emb[n]
#pragma unroll 1
      for (int it = lane; it < L * 32; it += NT) {
        int t = it >> 5, k = it & 31;
        s_ch[t * 36 + k] =
            fmaxf(fmaf(s_dd[t], cond_w1[n * 32 + k], cond_b1[n * 32 + k]), 0.0f);
      }
      SYNC();
      if (lane < L * 8) {
        int t = lane >> 3, c = lane & 7;
        s_emb[n * 64 + t * 8 + c] =
            cond_b2[n * 8 + c] +
            dotv2<8>(cond_w2 + (size_t)(n * 8 + c) * 32, s_ch + t * 36);
      }
      SYNC();
    }
  }
}

extern "C" void kernel_launch(void* const* d_in, const int* in_sizes, int n_in,
                              void* d_out, int out_size, void* d_ws, size_t ws_size,
                              hipStream_t stream) {
  const float* z       = (const float*)d_in[0];
  const float* cond_w1 = (const float*)d_in[1];
  const float* cond_b1 = (const float*)d_in[2];
  const float* cond_w2 = (const float*)d_in[3];
  const float* cond_b2 = (const float*)d_in[4];
  const float* proj_w  = (const float*)d_in[5];
  const float* proj_b  = (const float*)d_in[6];
  const float* gpw     = (const float*)d_in[7];
  const float* gpb     = (const float*)d_in[8];
  const float* gru_wih = (const float*)d_in[9];
  const float* gru_whh = (const float*)d_in[10];
  const float* gru_bih = (const float*)d_in[11];
  const float* gru_bhh = (const float*)d_in[12];
  const float* cm_w1   = (const float*)d_in[13];
  const float* cm_b1   = (const float*)d_in[14];
  const float* cm_w2   = (const float*)d_in[15];
  const float* cm_b2   = (const float*)d_in[16];
  const float* cm_w3   = (const float*)d_in[17];
  const float* cm_b3   = (const float*)d_in[18];
  const int*   endw    = (const int*)d_in[19];
  float* out = (float*)d_out;

  int Btot = in_sizes[0] / (8 * 8 * 32);  // z: [8, B, 8, 32]

  tcm_kernel<<<Btot, NT, 0, stream>>>(
      z, cond_w1, cond_b1, cond_w2, cond_b2, proj_w, proj_b, gpw, gpb,
      gru_wih, gru_whh, gru_bih, gru_bhh, cm_w1, cm_b1, cm_w2, cm_b2,
      cm_w3, cm_b3, endw, out, Btot);
}

// Round 14
// 1023.623 us; speedup vs baseline: 1.1366x; 1.0979x over previous
//
#include <hip/hip_runtime.h>

// TemporalCausalMaps on MI355X (gfx950), round 17 — FINAL.
// = round 8 verbatim, the session's harness-verified best (1025.7us).
// Structure: 1 wave/block (2048 blocks, 2 waves/SIMD), idx-outer/n-inner,
//  - ILP'd dots (2-4 accumulators; gates/cm1/cm2 t-pair unrolled)     [r7]
//  - cond-net computed once per decoded row into s_emb                [r7]
//  - lgkm-only SYNC (no barrier, no vmcnt drain; single wave)         [r8]
//  - cross-stage weight prefetch (loads issued a stage early, stay
//    in flight across SYNCs)                                          [r8]
// Verdict from rounds 9-16: at 2 instruction streams/SIMD (grid-capped),
// every variant that adds instructions (readlane rec, dual-sample lane
// replication), barriers (2-wave t-split), or register pressure
// (cross-stage residency, constexpr-L full unroll) regresses. This is a
// latency/serial-dependency floor at fixed stream count, not a HW roofline.

#define NT 64
#define SYNC() asm volatile("s_waitcnt lgkmcnt(0)" ::: "memory")

__device__ __forceinline__ float sigm(float x) { return 1.0f / (1.0f + __expf(-x)); }
__device__ __forceinline__ float tanh_fast(float x) {
  x = fminf(15.0f, fmaxf(-15.0f, x));
  float e = __expf(2.0f * x);
  return (e - 1.0f) / (e + 1.0f);
}
__device__ __forceinline__ float leaky(float x) { return x >= 0.0f ? x : 0.01f * x; }

template <int N4>
__device__ __forceinline__ float dotv2(const float* __restrict__ w, const float* h) {
  const float4* w4 = reinterpret_cast<const float4*>(w);
  const float4* h4 = reinterpret_cast<const float4*>(h);
  float a0 = 0.0f, a1 = 0.0f;
#pragma unroll
  for (int i = 0; i < N4; i += 2) {
    float4 x0 = w4[i], y0 = h4[i];
    float4 x1 = w4[i + 1], y1 = h4[i + 1];
    a0 = fmaf(x0.x, y0.x, a0); a0 = fmaf(x0.y, y0.y, a0);
    a0 = fmaf(x0.z, y0.z, a0); a0 = fmaf(x0.w, y0.w, a0);
    a1 = fmaf(x1.x, y1.x, a1); a1 = fmaf(x1.y, y1.y, a1);
    a1 = fmaf(x1.z, y1.z, a1); a1 = fmaf(x1.w, y1.w, a1);
  }
  return a0 + a1;
}

template <int N4>
__device__ __forceinline__ float dotv4(const float* __restrict__ w, const float* h) {
  const float4* w4 = reinterpret_cast<const float4*>(w);
  const float4* h4 = reinterpret_cast<const float4*>(h);
  float a0 = 0.0f, a1 = 0.0f, a2 = 0.0f, a3 = 0.0f;
#pragma unroll
  for (int i = 0; i < N4; i += 4) {
    float4 x0 = w4[i], y0 = h4[i];
    float4 x1 = w4[i + 1], y1 = h4[i + 1];
    float4 x2 = w4[i + 2], y2 = h4[i + 2];
    float4 x3 = w4[i + 3], y3 = h4[i + 3];
    a0 = fmaf(x0.x, y0.x, a0); a0 = fmaf(x0.y, y0.y, a0);
    a0 = fmaf(x0.z, y0.z, a0); a0 = fmaf(x0.w, y0.w, a0);
    a1 = fmaf(x1.x, y1.x, a1); a1 = fmaf(x1.y, y1.y, a1);
    a1 = fmaf(x1.z, y1.z, a1); a1 = fmaf(x1.w, y1.w, a1);
    a2 = fmaf(x2.x, y2.x, a2); a2 = fmaf(x2.y, y2.y, a2);
    a2 = fmaf(x2.z, y2.z, a2); a2 = fmaf(x2.w, y2.w, a2);
    a3 = fmaf(x3.x, y3.x, a3); a3 = fmaf(x3.y, y3.y, a3);
    a3 = fmaf(x3.w, y3.w, a3); a3 = fmaf(x3.z, y3.z, a3);
  }
  return (a0 + a1) + (a2 + a3);
}

// ---- weight loaders (prefetch points) ----
__device__ __forceinline__ void load_gates_w(
    const float* __restrict__ wih, const float* __restrict__ bih,
    int lane, int rowB, float4 WA[6], float4 WB[6], float& bA, float& bB) {
  const float4* wa = reinterpret_cast<const float4*>(wih + (size_t)lane * 24);
  const float4* wb = reinterpret_cast<const float4*>(wih + (size_t)rowB * 24);
#pragma unroll
  for (int i = 0; i < 6; ++i) { WA[i] = wa[i]; WB[i] = wb[i]; }
  bA = bih[lane]; bB = bih[rowB];
}

__device__ __forceinline__ void load_rec_w(
    const float* __restrict__ whh, const float* __restrict__ bhh,
    int jq, int half, float4 Wr[3], float4 Wz[3], float4 Wn[3],
    float& bR, float& bZ, float& bN) {
  const float4* wr = reinterpret_cast<const float4*>(whh + jq * 24 + half * 12);
  const float4* wz = reinterpret_cast<const float4*>(whh + (24 + jq) * 24 + half * 12);
  const float4* wn = reinterpret_cast<const float4*>(whh + (48 + jq) * 24 + half * 12);
#pragma unroll
  for (int i = 0; i < 3; ++i) { Wr[i] = wr[i]; Wz[i] = wz[i]; Wn[i] = wn[i]; }
  bR = half ? 0.0f : bhh[jq];
  bZ = half ? 0.0f : bhh[24 + jq];
  bN = half ? 0.0f : bhh[48 + jq];
}

// ---- compute stages (weights already in regs) ----
__device__ __forceinline__ void gates_comp(
    const float4 WA[6], const float4 WB[6], float bA, float bB,
    const float* srcp, float* s_gi, int L, int lane) {
  int t = 0;
#pragma unroll 1
  for (; t + 1 < L; t += 2) {
    const float4* h0 = reinterpret_cast<const float4*>(srcp + t * 24);
    const float4* h1 = reinterpret_cast<const float4*>(srcp + t * 24 + 24);
    float a0 = bA, a1 = bA, c0 = bB, c1 = bB;
#pragma unroll
    for (int i = 0; i < 6; ++i) {
      float4 p = h0[i], q = h1[i], A = WA[i], Bv = WB[i];
      a0 = fmaf(A.x, p.x, a0); a0 = fmaf(A.y, p.y, a0);
      a0 = fmaf(A.z, p.z, a0); a0 = fmaf(A.w, p.w, a0);
      a1 = fmaf(A.x, q.x, a1); a1 = fmaf(A.y, q.y, a1);
      a1 = fmaf(A.z, q.z, a1); a1 = fmaf(A.w, q.w, a1);
      c0 = fmaf(Bv.x, p.x, c0); c0 = fmaf(Bv.y, p.y, c0);
      c0 = fmaf(Bv.z, p.z, c0); c0 = fmaf(Bv.w, p.w, c0);
      c1 = fmaf(Bv.x, q.x, c1); c1 = fmaf(Bv.y, q.y, c1);
      c1 = fmaf(Bv.z, q.z, c1); c1 = fmaf(Bv.w, q.w, c1);
    }
    s_gi[t * 72 + lane] = a0;
    s_gi[t * 72 + 72 + lane] = a1;
    if (lane < 8) {
      s_gi[t * 72 + 64 + lane] = c0;
      s_gi[t * 72 + 136 + lane] = c1;
    }
  }
  if (t < L) {
    const float4* h0 = reinterpret_cast<const float4*>(srcp + t * 24);
    float a0 = bA, c0 = bB;
#pragma unroll
    for (int i = 0; i < 6; ++i) {
      float4 p = h0[i], A = WA[i], Bv = WB[i];
      a0 = fmaf(A.x, p.x, a0); a0 = fmaf(A.y, p.y, a0);
      a0 = fmaf(A.z, p.z, a0); a0 = fmaf(A.w, p.w, a0);
      c0 = fmaf(Bv.x, p.x, c0); c0 = fmaf(Bv.y, p.y, c0);
      c0 = fmaf(Bv.z, p.z, c0); c0 = fmaf(Bv.w, p.w, c0);
    }
    s_gi[t * 72 + lane] = a0;
    if (lane < 8) s_gi[t * 72 + 64 + lane] = c0;
  }
}

__device__ __forceinline__ void rec_comp(
    const float4 Wr[3], const float4 Wz[3], const float4 Wn[3],
    float bR, float bZ, float bN,
    const float* s_gi, float* s_hid, float* s_y, int L, int lane, int jq, int half) {
  if (lane < 24) s_hid[lane] = 0.0f;
  int cur = 0;
#pragma unroll 1
  for (int t = 0; t < L; ++t) {
    const float4* hp = reinterpret_cast<const float4*>(s_hid + cur * 24 + half * 12);
    float gr = bR, gz = bZ, gn = bN;
#pragma unroll
    for (int i = 0; i < 3; ++i) {
      float4 hh = hp[i];
      gr = fmaf(Wr[i].x, hh.x, gr); gr = fmaf(Wr[i].y, hh.y, gr);
      gr = fmaf(Wr[i].z, hh.z, gr); gr = fmaf(Wr[i].w, hh.w, gr);
      gz = fmaf(Wz[i].x, hh.x, gz); gz = fmaf(Wz[i].y, hh.y, gz);
      gz = fmaf(Wz[i].z, hh.z, gz); gz = fmaf(Wz[i].w, hh.w, gz);
      gn = fmaf(Wn[i].x, hh.x, gn); gn = fmaf(Wn[i].y, hh.y, gn);
      gn = fmaf(Wn[i].z, hh.z, gn); gn = fmaf(Wn[i].w, hh.w, gn);
    }
    gr += __shfl_xor(gr, 32);
    gz += __shfl_xor(gz, 32);
    gn += __shfl_xor(gn, 32);
    const float* gi = s_gi + t * 72;
    float r   = sigm(gi[jq] + gr);
    float zg  = sigm(gi[24 + jq] + gz);
    float nn2 = tanh_fast(gi[48 + jq] + r * gn);
    float hold = s_hid[cur * 24 + jq];
    float hnew = fmaf(zg, hold - nn2, nn2);  // (1-z)*n + z*h
    if (lane < 24) {
      s_hid[(cur ^ 1) * 24 + lane] = hnew;
      s_y[t * 24 + lane] = hnew;
    }
    cur ^= 1;
  }
}

// LDS layout (floats). Total 3488 floats = 13952 B.
//  s_x   [8][48] @0      s_h  [8][24] @384    s_g   [8][24] @576
//  s_gi  [8][72] @768    s_y  [8][24] @1344   s_hid [2][24] @1536
//  s_d1  [8][68] @1584   s_d2 [8][68] @2128   s_dd  [16]    @2672
//  s_ch  [8][36] @2688   s_emb[8][8][8] @2976
__global__ __launch_bounds__(NT, 2) void tcm_kernel(
    const float* __restrict__ z,
    const float* __restrict__ cond_w1, const float* __restrict__ cond_b1,
    const float* __restrict__ cond_w2, const float* __restrict__ cond_b2,
    const float* __restrict__ proj_w, const float* __restrict__ proj_b,
    const float* __restrict__ gpw, const float* __restrict__ gpb,
    const float* __restrict__ gru_wih, const float* __restrict__ gru_whh,
    const float* __restrict__ gru_bih, const float* __restrict__ gru_bhh,
    const float* __restrict__ cm_w1, const float* __restrict__ cm_b1,
    const float* __restrict__ cm_w2, const float* __restrict__ cm_b2,
    const float* __restrict__ cm_w3, const float* __restrict__ cm_b3,
    const int* __restrict__ endw,
    float* __restrict__ out, int Btot) {
  __shared__ __align__(16) float lds[3488];
  float* s_x   = lds;
  float* s_h   = lds + 384;
  float* s_g   = lds + 576;
  float* s_gi  = lds + 768;
  float* s_y   = lds + 1344;
  float* s_hid = lds + 1536;
  float* s_d1  = lds + 1584;   // stride 68
  float* s_d2  = lds + 2128;   // stride 68
  float* s_dd  = lds + 2672;
  float* s_ch  = lds + 2688;   // stride 36
  float* s_emb = lds + 2976;   // [n][t][c] = n*64 + t*8 + c

  const int lane = threadIdx.x;
  const int b = blockIdx.x;
  const int T = endw[0];
  const int jm = lane & 31;
  const int half = lane >> 5;
  const int jq = jm < 24 ? jm : 0;
  const int rowB = 64 + (lane & 7);

#pragma unroll 1
  for (int idx = 0; idx < T; ++idx) {
    const int L = idx + 1;
#pragma unroll 1
    for (int n = 0; n < 8; ++n) {
      const float* wih0 = gru_wih + (size_t)(n * 2) * 1728;
      const float* wih1 = wih0 + 1728;
      const float* whh0 = gru_whh + (size_t)(n * 2) * 1728;
      const float* whh1 = whh0 + 1728;
      const float* bih0 = gru_bih + (n * 2) * 72;
      const float* bih1 = bih0 + 72;
      const float* bhh0 = gru_bhh + (n * 2) * 72;
      const float* bhh1 = bhh0 + 72;

      // prefetch gates-L0 weights (used after proj/gproj)
      float4 WA[6], WB[6]; float bA, bB;
      load_gates_w(wih0, bih0, lane, rowB, WA, WB, bA, bB);

      // ---- phase A: s_x = [z | emb_self | emb_pred]
      if (lane < L * 8) {
        const float4* z4 = reinterpret_cast<const float4*>(
            z + ((size_t)n * Btot + b) * 8 * 32);
        int t = lane >> 3, q = lane & 7;
        reinterpret_cast<float4*>(s_x)[t * 12 + q] = z4[t * 8 + q];
      }
#pragma unroll 1
      for (int it = lane; it < L * 16; it += NT) {
        int t = it >> 4, c = it & 15;
        float v = 0.0f;
        if (c < 8) {
          if (t < idx) v = s_emb[n * 64 + t * 8 + c];
        } else {
          if (n > 0 && idx > 0) v = s_emb[(n - 1) * 64 + t * 8 + (c - 8)];
        }
        s_x[t * 48 + 32 + c] = v;
      }
      SYNC();
      // ---- proj -> leaky
#pragma unroll 1
      for (int it = lane; it < L * 24; it += NT) {
        int t = it / 24, j = it - t * 24;
        float acc = proj_b[n * 24 + j] +
                    dotv2<12>(proj_w + (size_t)(n * 24 + j) * 48, s_x + t * 48);
        s_h[t * 24 + j] = leaky(acc);
      }
      SYNC();
      // ---- gru_proj
#pragma unroll 1
      for (int it = lane; it < L * 24; it += NT) {
        int t = it / 24, j = it - t * 24;
        s_g[t * 24 + j] = gpb[j] + dotv2<6>(gpw + j * 24, s_h + t * 24);
      }
      SYNC();
      // prefetch rec-L0 weights (in flight during gates L0)
      float4 Wr[3], Wz[3], Wn[3]; float bR, bZ, bN;
      load_rec_w(whh0, bhh0, jq, half, Wr, Wz, Wn, bR, bZ, bN);
      // ---- gates L0
      gates_comp(WA, WB, bA, bB, s_g, s_gi, L, lane);
      SYNC();
      // prefetch gates-L1 weights (in flight during rec L0)
      float4 WA1[6], WB1[6]; float bA1, bB1;
      load_gates_w(wih1, bih1, lane, rowB, WA1, WB1, bA1, bB1);
      // ---- rec L0 -> s_y
      rec_comp(Wr, Wz, Wn, bR, bZ, bN, s_gi, s_hid, s_y, L, lane, jq, half);
      SYNC();
      // prefetch rec-L1 weights (in flight during gates L1)
      float4 Wr1[3], Wz1[3], Wn1[3]; float bR1, bZ1, bN1;
      load_rec_w(whh1, bhh1, jq, half, Wr1, Wz1, Wn1, bR1, bZ1, bN1);
      // ---- gates L1
      gates_comp(WA1, WB1, bA1, bB1, s_y, s_gi, L, lane);
      SYNC();
      // prefetch cm1 row (in flight during rec L1)
      float4 C1[6];
      {
        const float4* p = reinterpret_cast<const float4*>(
            cm_w1 + (size_t)(n * 64 + lane) * 24);
#pragma unroll
        for (int i = 0; i < 6; ++i) C1[i] = p[i];
      }
      const float c1b = cm_b1[n * 64 + lane];
      // ---- rec L1 -> s_y
      rec_comp(Wr1, Wz1, Wn1, bR1, bZ1, bN1, s_gi, s_hid, s_y, L, lane, jq, half);
      SYNC();
      // prefetch cm2 row (in flight during cm1)
      float4 C2[16];
      {
        const float4* p = reinterpret_cast<const float4*>(
            cm_w2 + (size_t)(n * 64 + lane) * 64);
#pragma unroll
        for (int i = 0; i < 16; ++i) C2[i] = p[i];
      }
      const float c2b = cm_b2[n * 64 + lane];
      // ---- cm1: lane = j, t unrolled by 2
      {
        int t = 0;
#pragma unroll 1
        for (; t + 1 < L; t += 2) {
          const float4* y0 = reinterpret_cast<const float4*>(s_y + t * 24);
          const float4* y1 = reinterpret_cast<const float4*>(s_y + t * 24 + 24);
          float a0 = c1b, a1 = c1b;
#pragma unroll
          for (int i = 0; i < 6; ++i) {
            float4 pp = y0[i], q = y1[i], W = C1[i];
            a0 = fmaf(W.x, pp.x, a0); a0 = fmaf(W.y, pp.y, a0);
            a0 = fmaf(W.z, pp.z, a0); a0 = fmaf(W.w, pp.w, a0);
            a1 = fmaf(W.x, q.x, a1); a1 = fmaf(W.y, q.y, a1);
            a1 = fmaf(W.z, q.z, a1); a1 = fmaf(W.w, q.w, a1);
          }
          s_d1[t * 68 + lane] = fmaxf(a0, 0.0f);
          s_d1[t * 68 + 68 + lane] = fmaxf(a1, 0.0f);
        }
        if (t < L) {
          float acc = c1b;
          const float4* y0 = reinterpret_cast<const float4*>(s_y + t * 24);
#pragma unroll
          for (int i = 0; i < 6; ++i) {
            float4 pp = y0[i], W = C1[i];
            acc = fmaf(W.x, pp.x, acc); acc = fmaf(W.y, pp.y, acc);
            acc = fmaf(W.z, pp.z, acc); acc = fmaf(W.w, pp.w, acc);
          }
          s_d1[t * 68 + lane] = fmaxf(acc, 0.0f);
        }
      }
      SYNC();
      // ---- cm2: lane = j, t unrolled by 2, 2 accs per t
      {
        int t = 0;
#pragma unroll 1
        for (; t + 1 < L; t += 2) {
          const float4* d0 = reinterpret_cast<const float4*>(s_d1 + t * 68);
          const float4* d1 = reinterpret_cast<const float4*>(s_d1 + t * 68 + 68);
          float a0 = c2b, a1 = 0.0f, c0 = c2b, c1 = 0.0f;
#pragma unroll
          for (int i = 0; i < 16; i += 2) {
            float4 W0 = C2[i], W1 = C2[i + 1];
            float4 p0 = d0[i], p1 = d0[i + 1], q0 = d1[i], q1 = d1[i + 1];
            a0 = fmaf(W0.x, p0.x, a0); a0 = fmaf(W0.y, p0.y, a0);
            a0 = fmaf(W0.z, p0.z, a0); a0 = fmaf(W0.w, p0.w, a0);
            a1 = fmaf(W1.x, p1.x, a1); a1 = fmaf(W1.y, p1.y, a1);
            a1 = fmaf(W1.z, p1.z, a1); a1 = fmaf(W1.w, p1.w, a1);
            c0 = fmaf(W0.x, q0.x, c0); c0 = fmaf(W0.y, q0.y, c0);
            c0 = fmaf(W0.z, q0.z, c0); c0 = fmaf(W0.w, q0.w, c0);
            c1 = fmaf(W1.x, q1.x, c1); c1 = fmaf(W1.y, q1.y, c1);
            c1 = fmaf(W1.z, q1.z, c1); c1 = fmaf(W1.w, q1.w, c1);
          }
          s_d2[t * 68 + lane] = fmaxf(a0 + a1, 0.0f);
          s_d2[t * 68 + 68 + lane] = fmaxf(c0 + c1, 0.0f);
        }
        if (t < L) {
          const float4* d0 = reinterpret_cast<const float4*>(s_d1 + t * 68);
          float a0 = c2b, a1 = 0.0f;
#pragma unroll
          for (int i = 0; i < 16; i += 2) {
            float4 W0 = C2[i], W1 = C2[i + 1];
            float4 p0 = d0[i], p1 = d0[i + 1];
            a0 = fmaf(W0.x, p0.x, a0); a0 = fmaf(W0.y, p0.y, a0);
            a0 = fmaf(W0.z, p0.z, a0); a0 = fmaf(W0.w, p0.w, a0);
            a1 = fmaf(W1.x, p1.x, a1); a1 = fmaf(W1.y, p1.y, a1);
            a1 = fmaf(W1.z, p1.z, a1); a1 = fmaf(W1.w, p1.w, a1);
          }
          s_d2[t * 68 + lane] = fmaxf(a0 + a1, 0.0f);
        }
      }
      SYNC();
      // ---- cm3 -> decoded row + emit
      if (lane < L) {
        int t = lane;
        float dv = cm_b3[n] + dotv4<16>(cm_w3 + n * 64, s_d2 + t * 68);
        s_dd[t] = dv;
        if (t == idx)
          out[((size_t)b * T + idx) * 8 + n] = dv;
      }
      SYNC();
      // ---- cond-net ONCE per decoded row -> s_emb[n]
#pragma unroll 1
      for (int it = lane; it < L * 32; it += NT) {
        int t = it >> 5, k = it & 31;
        s_ch[t * 36 + k] =
            fmaxf(fmaf(s_dd[t], cond_w1[n * 32 + k], cond_b1[n * 32 + k]), 0.0f);
      }
      SYNC();
      if (lane < L * 8) {
        int t = lane >> 3, c = lane & 7;
        s_emb[n * 64 + t * 8 + c] =
            cond_b2[n * 8 + c] +
            dotv2<8>(cond_w2 + (size_t)(n * 8 + c) * 32, s_ch + t * 36);
      }
      SYNC();
    }
  }
}

extern "C" void kernel_launch(void* const* d_in, const int* in_sizes, int n_in,
                              void* d_out, int out_size, void* d_ws, size_t ws_size,
                              hipStream_t stream) {
  const float* z       = (const float*)d_in[0];
  const float* cond_w1 = (const float*)d_in[1];
  const float* cond_b1 = (const float*)d_in[2];
  const float* cond_w2 = (const float*)d_in[3];
  const float* cond_b2 = (const float*)d_in[4];
  const float* proj_w  = (const float*)d_in[5];
  const float* proj_b  = (const float*)d_in[6];
  const float* gpw     = (const float*)d_in[7];
  const float* gpb     = (const float*)d_in[8];
  const float* gru_wih = (const float*)d_in[9];
  const float* gru_whh = (const float*)d_in[10];
  const float* gru_bih = (const float*)d_in[11];
  const float* gru_bhh = (const float*)d_in[12];
  const float* cm_w1   = (const float*)d_in[13];
  const float* cm_b1   = (const float*)d_in[14];
  const float* cm_w2   = (const float*)d_in[15];
  const float* cm_b2   = (const float*)d_in[16];
  const float* cm_w3   = (const float*)d_in[17];
  const float* cm_b3   = (const float*)d_in[18];
  const int*   endw    = (const int*)d_in[19];
  float* out = (float*)d_out;

  int Btot = in_sizes[0] / (8 * 8 * 32);  // z: [8, B, 8, 32]

  tcm_kernel<<<Btot, NT, 0, stream>>>(
      z, cond_w1, cond_b1, cond_w2, cond_b2, proj_w, proj_b, gpw, gpb,
      gru_wih, gru_whh, gru_bih, gru_bhh, cm_w1, cm_b1, cm_w2, cm_b2,
      cm_w3, cm_b3, endw, out, Btot);
}